// Round 11
// baseline (120.696 us; speedup 1.0000x reference)
//
#include <hip/hip_runtime.h>
#include <stdint.h>

#define N_IMG 32
#define P_TOT 8400
#define NCLS 80
#define NMS_PRE 1000
#define MAXOUT 100
#define SCORE_THRF 0.01f
#define NMS_THRF 0.65f
#define CAND_N 2048
#define NB 512          // histogram bins over dk>>17
#define BINBASE 8192    // valid masked scores [0.01,1.0] -> dk>>17 in [8255,8686] strictly inside [8192,8704)
#define TIE_EPS 0.05f   // sigmoid float-rounding tie window (validated R9/R10, absmax 0)
#define NBATCH 8
#define BSZ 10

// Level layout: p in [0,6400): 80x80 s=8 ; [6400,8000): 40x40 s=16 ; [8000,8400): 20x20 s=32

__device__ __forceinline__ float sigmoidf_(float x) { return 1.0f / (1.0f + expf(-x)); }

// ---------------- Kernel 1: scores -> sort keys (batched loads, forced MLP=10) ----------------
// Thread owns 2 consecutive anchors (float2 loads, 512B/wave). 8 batches x 10 loads into
// distinct regs, pinned via sched_group_barrier(VMEM_READ,10) so 10 requests are in flight.
// Hot loop is pure fmax (logit max); exact sigmoid-argmax via tie-window batch reload
// (cache-hot): batches with bmax >= gmax-TIE_EPS are rescanned with packed sigmoid keys.
__global__ __launch_bounds__(256) void k_score(
    const float* __restrict__ cls0, const float* __restrict__ cls1, const float* __restrict__ cls2,
    const float* __restrict__ obj0, const float* __restrict__ obj1, const float* __restrict__ obj2,
    uint64_t* __restrict__ keys)
{
    int t = blockIdx.x * 256 + threadIdx.x;   // 0..134399 exact
    int a0 = t * 2;                            // first of 2 consecutive anchors (same image+level)
    int n = a0 / P_TOT;
    int p = a0 - n * P_TOT;                    // even; level boundaries 6400/8000/8400 are even

    const float* cl; const float* ob; int HW, q;
    if (p < 6400)      { cl = cls0; ob = obj0; HW = 6400; q = p; }
    else if (p < 8000) { cl = cls1; ob = obj1; HW = 1600; q = p - 6400; }
    else               { cl = cls2; ob = obj2; HW = 400;  q = p - 8000; }

    const float* cbase = cl + (size_t)n * NCLS * HW + q;

    float bmx[NBATCH], bmy[NBATCH];
    float gx = -3.4e38f, gy = -3.4e38f;
    #pragma unroll
    for (int b = 0; b < NBATCH; ++b) {
        float2 v[BSZ];
        #pragma unroll
        for (int i = 0; i < BSZ; ++i)
            v[i] = *reinterpret_cast<const float2*>(cbase + (size_t)(b * BSZ + i) * HW);
        __builtin_amdgcn_sched_group_barrier(0x20, BSZ, 0);   // pin 10 VMEM reads together
        // fmax tree (depth 4) — needs all 10 live
        float ax0 = fmaxf(v[0].x, v[1].x), ax1 = fmaxf(v[2].x, v[3].x);
        float ax2 = fmaxf(v[4].x, v[5].x), ax3 = fmaxf(v[6].x, v[7].x);
        float ax4 = fmaxf(v[8].x, v[9].x);
        float ay0 = fmaxf(v[0].y, v[1].y), ay1 = fmaxf(v[2].y, v[3].y);
        float ay2 = fmaxf(v[4].y, v[5].y), ay3 = fmaxf(v[6].y, v[7].y);
        float ay4 = fmaxf(v[8].y, v[9].y);
        float bx = fmaxf(fmaxf(fmaxf(ax0, ax1), fmaxf(ax2, ax3)), ax4);
        float by = fmaxf(fmaxf(fmaxf(ay0, ay1), fmaxf(ay2, ay3)), ay4);
        bmx[b] = bx; bmy[b] = by;
        gx = fmaxf(gx, bx); gy = fmaxf(gy, by);
    }

    // tie-window rescan: batches possibly containing a sigmoid-tying class (cache-hot)
    float tx = gx - TIE_EPS, ty = gy - TIE_EPS;
    uint64_t m0 = 0, m1 = 0;
    #pragma unroll
    for (int b = 0; b < NBATCH; ++b) {
        bool need = (bmx[b] >= tx) || (bmy[b] >= ty);
        if (__any(need)) {                      // wave-uniform branch, coalesced hot reloads
            #pragma unroll
            for (int i = 0; i < BSZ; ++i) {
                float2 v = *reinterpret_cast<const float2*>(cbase + (size_t)(b * BSZ + i) * HW);
                uint32_t ct = (uint32_t)(79 - (b * BSZ + i));
                if (v.x >= tx) { uint64_t pk = ((uint64_t)__float_as_uint(sigmoidf_(v.x)) << 8) | ct; m0 = m0 > pk ? m0 : pk; }
                if (v.y >= ty) { uint64_t pk = ((uint64_t)__float_as_uint(sigmoidf_(v.y)) << 8) | ct; m1 = m1 > pk ? m1 : pk; }
            }
        }
    }

    float2 ov = *reinterpret_cast<const float2*>(ob + (size_t)n * HW + q);
    float sox = sigmoidf_(ov.x), soy = sigmoidf_(ov.y);
    uint64_t kk[2];
    {
        float best = __uint_as_float((uint32_t)(m0 >> 8));   // = max_c sigmoid, exact
        int bc = 79 - (int)(m0 & 0xFFu);
        float sc = __fmul_rn(best, sox);
        float masked = (sc >= SCORE_THRF) ? sc : -1.0f;
        uint32_t u = __float_as_uint(masked);
        uint32_t ord = (u & 0x80000000u) ? ~u : (u | 0x80000000u);
        kk[0] = ((uint64_t)(~ord) << 32) | (uint32_t)((p << 8) | bc);
    }
    {
        float best = __uint_as_float((uint32_t)(m1 >> 8));
        int bc = 79 - (int)(m1 & 0xFFu);
        float sc = __fmul_rn(best, soy);
        float masked = (sc >= SCORE_THRF) ? sc : -1.0f;
        uint32_t u = __float_as_uint(masked);
        uint32_t ord = (u & 0x80000000u) ? ~u : (u | 0x80000000u);
        kk[1] = ((uint64_t)(~ord) << 32) | (uint32_t)(((p + 1) << 8) | bc);
    }
    *reinterpret_cast<ulonglong2*>(keys + a0) = make_ulonglong2(kk[0], kk[1]);
}

// ---------------- Kernel 2: counting-sort top-1000 keys ----------------
__global__ __launch_bounds__(1024) void k_select(
    const uint64_t* __restrict__ keys,
    uint64_t* __restrict__ skeys, int* __restrict__ nvalid)
{
    __shared__ uint32_t hist[NB];
    __shared__ uint32_t base[NB];
    __shared__ uint32_t fill[NB];
    __shared__ uint64_t grouped[CAND_N];   // bin-grouped candidates (16 KiB)
    __shared__ uint64_t cand[CAND_N];      // rank-ordered keys (16 KiB)
    __shared__ int      s_misc[2];         // [0]=Bcut, [1]=target(V)

    int n = blockIdx.x, tid = threadIdx.x;

    if (tid < NB) { hist[tid] = 0; fill[tid] = 0; }
    for (int t = tid; t < CAND_N; t += 1024) cand[t] = ~0ull;
    __syncthreads();

    // pass 1: histogram valid keys
    #pragma unroll
    for (int it = 0; it < 9; ++it) {
        int t = tid + it * 1024;
        if (t < P_TOT) {
            uint64_t k = keys[(size_t)n * P_TOT + t];
            uint32_t dk = (uint32_t)(k >> 32);
            if (!(dk & 0x80000000u)) atomicAdd(&hist[(dk >> 17) - BINBASE], 1u);
        }
    }
    __syncthreads();

    // wave-0 prefix over 512 bins: per-bin exclusive base, total, cutoff bin
    if (tid < 64) {
        uint32_t c[8]; uint32_t s = 0;
        #pragma unroll
        for (int i = 0; i < 8; ++i) { c[i] = hist[tid * 8 + i]; s += c[i]; }
        uint32_t inc = s;
        #pragma unroll
        for (int o = 1; o < 64; o <<= 1) {
            uint32_t v = __shfl_up(inc, o);
            if (tid >= o) inc += v;
        }
        uint32_t excl = inc - s;
        uint32_t b = excl;
        #pragma unroll
        for (int i = 0; i < 8; ++i) { base[tid * 8 + i] = b; b += c[i]; }
        uint32_t total = __shfl(inc, 63);
        uint32_t target = total < (uint32_t)NMS_PRE ? total : (uint32_t)NMS_PRE;
        uint32_t cum = excl; int found = 0x7fffffff;
        #pragma unroll
        for (int i = 0; i < 8; ++i) {
            cum += c[i];
            if (found == 0x7fffffff && cum >= target && target > 0) found = tid * 8 + i;
        }
        #pragma unroll
        for (int o = 32; o > 0; o >>= 1) { int f = __shfl_xor(found, o); found = f < found ? f : found; }
        if (tid == 0) { s_misc[0] = (total > 0) ? found : -1; s_misc[1] = (int)target; }
    }
    __syncthreads();
    int Bcut = s_misc[0];

    // pass 2: scatter candidates (bins <= Bcut) into bin-grouped order (keys L2-warm)
    #pragma unroll
    for (int it = 0; it < 9; ++it) {
        int t = tid + it * 1024;
        if (t < P_TOT) {
            uint64_t k = keys[(size_t)n * P_TOT + t];
            uint32_t dk = (uint32_t)(k >> 32);
            if (!(dk & 0x80000000u)) {
                int bin = (int)((dk >> 17) - BINBASE);
                if (bin <= Bcut) {
                    uint32_t pos = base[bin] + atomicAdd(&fill[bin], 1u);
                    if (pos < CAND_N) grouped[pos] = k;
                }
            }
        }
    }
    __syncthreads();

    // exact rank within bin (keys unique -> total order identical to full sort)
    int ccnt = 0;
    if (Bcut >= 0) {
        uint32_t cc = base[Bcut] + hist[Bcut];
        ccnt = cc < (uint32_t)CAND_N ? (int)cc : CAND_N;
    }
    for (int s = tid; s < ccnt; s += 1024) {
        uint64_t k = grouped[s];
        uint32_t dk = (uint32_t)(k >> 32);
        int bin = (int)((dk >> 17) - BINBASE);
        uint32_t b0 = base[bin];
        uint32_t e0 = b0 + hist[bin]; if (e0 > (uint32_t)CAND_N) e0 = CAND_N;
        uint32_t r = b0;
        for (uint32_t t = b0; t < e0; ++t) r += (grouped[t] < k) ? 1u : 0u;
        if (r < (uint32_t)CAND_N) cand[r] = k;
    }
    __syncthreads();

    if (tid < NMS_PRE) skeys[n * NMS_PRE + tid] = cand[tid];
    if (tid == 0) nvalid[n] = s_misc[1];
}

// ---------------- Kernel 3: decode + gmax + greedy NMS + output ----------------
__global__ __launch_bounds__(256) void k_nms(
    const uint64_t* __restrict__ skeys, const int* __restrict__ nvalid,
    const float* __restrict__ reg0, const float* __restrict__ reg1, const float* __restrict__ reg2,
    float* __restrict__ out)
{
    __shared__ float4 s_obx[NMS_PRE];   // offset boxes  (16000 B)
    __shared__ float4 s_raw[NMS_PRE];   // raw boxes     (16000 B)
    __shared__ float2 s_sl[NMS_PRE];    // score,label   ( 8000 B)
    __shared__ float  s_oar[NMS_PRE];   // offset areas  ( 4000 B)
    __shared__ float  fsh[4];
    __shared__ int    kidx[MAXOUT];

    int n = blockIdx.x, tid = threadIdx.x;
    int lane = tid & 63, wv = tid >> 6;
    int V = nvalid[n];

    // decode 4 anchors per thread (t = tid + 256*it), exactly like reference
    float4 bx4[4]; float lab4[4];
    float m = 0.f;
    #pragma unroll
    for (int it = 0; it < 4; ++it) {
        int t = tid + it * 256;
        float4 bx = make_float4(0.f, 0.f, 0.f, 0.f);
        float scm = -1.0f, labf = 0.f;
        if (t < NMS_PRE) {
            uint64_t key = skeys[n * NMS_PRE + t];
            uint32_t dk = (uint32_t)(key >> 32);
            if (!(dk & 0x80000000u)) {
                uint32_t low = (uint32_t)key;
                int lab = (int)(low & 0xFFu);
                int p   = (int)(low >> 8);
                uint32_t ord = ~dk;
                scm = __uint_as_float(ord ^ 0x80000000u);   // valid => positive float

                const float* rg; int HW, q, W; float s;
                if (p < 6400)      { rg = reg0; HW = 6400; q = p;        W = 80; s = 8.f; }
                else if (p < 8000) { rg = reg1; HW = 1600; q = p - 6400; W = 40; s = 16.f; }
                else               { rg = reg2; HW = 400;  q = p - 8000; W = 20; s = 32.f; }

                float px = (float)(q % W) * s;   // exact
                float py = (float)(q / W) * s;   // exact
                const float* rb = rg + (size_t)n * 4 * HW + q;
                float dx = rb[0], dy = rb[HW], dw = rb[2 * HW], dh = rb[3 * HW];
                float cx = __fadd_rn(__fmul_rn(dx, s), px);
                float cy = __fadd_rn(__fmul_rn(dy, s), py);
                float hw = __fmul_rn(__fmul_rn(expf(dw), s), 0.5f);
                float hh = __fmul_rn(__fmul_rn(expf(dh), s), 0.5f);
                bx.x = __fsub_rn(cx, hw); bx.y = __fsub_rn(cy, hh);
                bx.z = __fadd_rn(cx, hw); bx.w = __fadd_rn(cy, hh);
                labf = (float)lab;
                m = fmaxf(m, fmaxf(fmaxf(fabsf(bx.x), fabsf(bx.y)), fmaxf(fabsf(bx.z), fabsf(bx.w))));
            }
            s_raw[t] = bx;
            s_sl[t]  = make_float2(scm, labf);
        }
        bx4[it] = bx; lab4[it] = labf;
    }

    // gmax = max|b| over the 1000 gathered boxes (4-wave reduce)
    #pragma unroll
    for (int o = 32; o > 0; o >>= 1) m = fmaxf(m, __shfl_xor(m, o));
    if (lane == 0) fsh[wv] = m;
    __syncthreads();
    float gmax = fmaxf(fmaxf(fsh[0], fsh[1]), fmaxf(fsh[2], fsh[3]));

    // stage offset boxes
    #pragma unroll
    for (int it = 0; it < 4; ++it) {
        int t = tid + it * 256;
        if (t < NMS_PRE) {
            float off = __fmul_rn(lab4[it], __fadd_rn(gmax, 1.0f)); // lab * (max|b| + 1)
            float x1 = __fadd_rn(bx4[it].x, off), y1 = __fadd_rn(bx4[it].y, off);
            float x2 = __fadd_rn(bx4[it].z, off), y2 = __fadd_rn(bx4[it].w, off);
            s_obx[t] = make_float4(x1, y1, x2, y2);
            s_oar[t] = __fmul_rn(__fsub_rn(x2, x1), __fsub_rn(y2, y1));
        }
    }
    __syncthreads();
    if (tid >= 64) return;      // wave 0 finishes alone

    // ---- greedy NMS: lanes = kept boxes; candidates serial with LDS-broadcast prefetch ----
    int count = 0;
    float k1x1 = 0.f, k1y1 = 0.f, k1x2 = 0.f, k1y2 = 0.f, k1a = 0.f;  // kept[lane]
    float k2x1 = 0.f, k2y1 = 0.f, k2x2 = 0.f, k2y2 = 0.f, k2a = 0.f;  // kept[lane+64]

    float4 nb = s_obx[0]; float na = s_oar[0];
    for (int i = 0; i < V && count < MAXOUT; ++i) {
        float4 cb = nb; float ca = na;
        int ip = (i + 1 < V) ? i + 1 : i;
        nb = s_obx[ip]; na = s_oar[ip];     // prefetch next candidate (indep of decision)

        bool sup = false;
        int c1 = count < 64 ? count : 64;
        if (lane < c1) {
            float ltx = fmaxf(k1x1, cb.x), lty = fmaxf(k1y1, cb.y);
            float rbx = fminf(k1x2, cb.z), rby = fminf(k1y2, cb.w);
            float w = fmaxf(__fsub_rn(rbx, ltx), 0.f);
            float h = fmaxf(__fsub_rn(rby, lty), 0.f);
            float inter = __fmul_rn(w, h);
            float denom = __fadd_rn(__fsub_rn(__fadd_rn(k1a, ca), inter), 1e-9f);
            sup = (inter / denom > NMS_THRF);
        }
        if (count > 64 && lane < count - 64) {
            float ltx = fmaxf(k2x1, cb.x), lty = fmaxf(k2y1, cb.y);
            float rbx = fminf(k2x2, cb.z), rby = fminf(k2y2, cb.w);
            float w = fmaxf(__fsub_rn(rbx, ltx), 0.f);
            float h = fmaxf(__fsub_rn(rby, lty), 0.f);
            float inter = __fmul_rn(w, h);
            float denom = __fadd_rn(__fsub_rn(__fadd_rn(k2a, ca), inter), 1e-9f);
            sup = sup || (inter / denom > NMS_THRF);
        }
        if (__ballot(sup) == 0ull) {
            if (lane == count)      { k1x1 = cb.x; k1y1 = cb.y; k1x2 = cb.z; k1y2 = cb.w; k1a = ca; }
            if (lane + 64 == count) { k2x1 = cb.x; k2y1 = cb.y; k2x2 = cb.z; k2y2 = cb.w; k2a = ca; }
            if (lane == 0) kidx[count] = i;
            ++count;
        }
    }

    float* ob = out;                          // [32*100*4]
    float* os = out + N_IMG * MAXOUT * 4;     // [32*100]
    float* ol = os + N_IMG * MAXOUT;          // [32*100] labels as float
    for (int mi = lane; mi < MAXOUT; mi += 64) {
        int o4 = (n * MAXOUT + mi) * 4;
        if (mi < count) {
            int i = kidx[mi];
            float4 b  = s_raw[i];
            float2 sl = s_sl[i];
            ob[o4 + 0] = b.x; ob[o4 + 1] = b.y; ob[o4 + 2] = b.z; ob[o4 + 3] = b.w;
            os[n * MAXOUT + mi] = sl.x;
            ol[n * MAXOUT + mi] = sl.y;
        } else {
            ob[o4 + 0] = 0.f; ob[o4 + 1] = 0.f; ob[o4 + 2] = 0.f; ob[o4 + 3] = 0.f;
            os[n * MAXOUT + mi] = 0.f;
            ol[n * MAXOUT + mi] = -1.f;
        }
    }
}

extern "C" void kernel_launch(void* const* d_in, const int* in_sizes, int n_in,
                              void* d_out, int out_size, void* d_ws, size_t ws_size,
                              hipStream_t stream)
{
    const float* cls0 = (const float*)d_in[0];
    const float* cls1 = (const float*)d_in[1];
    const float* cls2 = (const float*)d_in[2];
    const float* reg0 = (const float*)d_in[3];
    const float* reg1 = (const float*)d_in[4];
    const float* reg2 = (const float*)d_in[5];
    const float* obj0 = (const float*)d_in[6];
    const float* obj1 = (const float*)d_in[7];
    const float* obj2 = (const float*)d_in[8];

    uint64_t* keys  = (uint64_t*)d_ws;                              // 2.1 MB
    uint64_t* skeys = (uint64_t*)((char*)d_ws + (4u << 20));        // 256 KB
    int*     nvalid = (int*)((char*)d_ws + (4u << 20) + (512u << 10));
    float* out = (float*)d_out;

    k_score<<<525, 256, 0, stream>>>(
        cls0, cls1, cls2, obj0, obj1, obj2, keys);
    k_select<<<N_IMG, 1024, 0, stream>>>(keys, skeys, nvalid);
    k_nms<<<N_IMG, 256, 0, stream>>>(skeys, nvalid, reg0, reg1, reg2, out);
}

// Round 12
// 70.820 us; speedup vs baseline: 1.7043x; 1.7043x over previous
//
#include <hip/hip_runtime.h>
#include <stdint.h>

#define N_IMG 32
#define P_TOT 8400
#define NCLS 80
#define NMS_PRE 1000
#define MAXOUT 100
#define SCORE_THRF 0.01f
#define NMS_THRF 0.65f
#define CAND_N 2048
#define NB 512          // histogram bins over dk>>17
#define BINBASE 8192    // valid masked scores [0.01,1.0] -> dk>>17 in [8255,8686] strictly inside [8192,8704)
#define TIE_EPS 0.05f   // sigmoid float-rounding tie window (validated R9/R10, absmax 0)

// Level layout: p in [0,6400): 80x80 s=8 ; [6400,8000): 40x40 s=16 ; [8000,8400): 20x20 s=32

__device__ __forceinline__ float sigmoidf_(float x) { return 1.0f / (1.0f + expf(-x)); }

// ---------------- Kernel 1: scores -> sort keys (class-split waves, pinned 20-deep MLP) ----------------
// Block = 256 thr = 4 waves; 64 anchors/block; wave w covers classes [20w,20w+20).
// All 20 class loads pinned back-to-back (sched_group_barrier VMEM_READ) so 20 requests
// are in flight per wave. Tie-window rescan uses the REGISTER cache lg[20] — zero extra
// memory traffic (R11's mistake removed). Exact-label logic validated in R9/R10 (absmax 0).
__global__ __launch_bounds__(256) void k_score(
    const float* __restrict__ cls0, const float* __restrict__ cls1, const float* __restrict__ cls2,
    const float* __restrict__ obj0, const float* __restrict__ obj1, const float* __restrict__ obj2,
    uint64_t* __restrict__ keys)
{
    __shared__ float    pml[4][64];    // per-wave partial max logit
    __shared__ uint64_t part[4][64];   // per-wave partial packed sigmoid-argmax
    int lane = threadIdx.x & 63, wid = threadIdx.x >> 6;
    int a = blockIdx.x * 64 + lane;          // global anchor id, < 268800 exactly
    int n = a / P_TOT;
    int p = a - n * P_TOT;

    const float* cl; const float* ob; int HW, q;
    if (p < 6400)      { cl = cls0; ob = obj0; HW = 6400; q = p; }
    else if (p < 8000) { cl = cls1; ob = obj1; HW = 1600; q = p - 6400; }
    else               { cl = cls2; ob = obj2; HW = 400;  q = p - 8000; }

    const float* cbase = cl + (size_t)n * NCLS * HW + q;
    int c0 = wid * 20;

    // 20 independent loads into distinct registers, pinned as one VMEM burst
    float lg[20];
    #pragma unroll
    for (int i = 0; i < 20; ++i)
        lg[i] = cbase[(size_t)(c0 + i) * HW];
    __builtin_amdgcn_sched_group_barrier(0x20, 20, 0);   // 20 VMEM reads back-to-back

    // wide fmax tree (depth 5)
    float a0 = fmaxf(lg[0], lg[1]),  a1 = fmaxf(lg[2], lg[3]);
    float a2 = fmaxf(lg[4], lg[5]),  a3 = fmaxf(lg[6], lg[7]);
    float a4 = fmaxf(lg[8], lg[9]),  a5 = fmaxf(lg[10], lg[11]);
    float a6 = fmaxf(lg[12], lg[13]), a7 = fmaxf(lg[14], lg[15]);
    float a8 = fmaxf(lg[16], lg[17]), a9 = fmaxf(lg[18], lg[19]);
    float b0 = fmaxf(a0, a1), b1 = fmaxf(a2, a3), b2 = fmaxf(a4, a5);
    float b3 = fmaxf(a6, a7), b4 = fmaxf(a8, a9);
    float lmax = fmaxf(fmaxf(fmaxf(b0, b1), fmaxf(b2, b3)), b4);
    pml[wid][lane] = lmax;
    __syncthreads();

    // global max logit for this anchor, then tie-window rescan of the register cache
    float gmaxl = fmaxf(fmaxf(pml[0][lane], pml[1][lane]),
                        fmaxf(pml[2][lane], pml[3][lane]));
    float thr = gmaxl - TIE_EPS;
    uint64_t m = 0;
    #pragma unroll
    for (int i = 0; i < 20; ++i) {
        if (lg[i] >= thr) {
            float s = sigmoidf_(lg[i]);
            uint64_t pk = ((uint64_t)__float_as_uint(s) << 8) | (uint32_t)(79 - (c0 + i));
            m = m > pk ? m : pk;    // equal sig -> lower class wins (= jnp.argmax)
        }
    }
    part[wid][lane] = m;
    __syncthreads();

    if (wid == 0) {
        uint64_t m0 = part[0][lane], m1 = part[1][lane];
        uint64_t m2 = part[2][lane], m3 = part[3][lane];
        uint64_t ma = m0 > m1 ? m0 : m1, mb = m2 > m3 ? m2 : m3;
        uint64_t mm = ma > mb ? ma : mb;
        float best = __uint_as_float((uint32_t)(mm >> 8));   // = max_c sigmoid(cls_c), exact
        int bc = 79 - (int)(mm & 0xFFu);

        float so = sigmoidf_(ob[(size_t)n * HW + q]);
        float sc = __fmul_rn(best, so);
        float masked = (sc >= SCORE_THRF) ? sc : -1.0f;
        uint32_t u = __float_as_uint(masked);
        uint32_t ord = (u & 0x80000000u) ? ~u : (u | 0x80000000u);
        uint32_t dk = ~ord;                  // descending (valid => top bit 0)
        keys[a] = ((uint64_t)dk << 32) | (uint32_t)((p << 8) | bc);
    }
}

// ---------------- Kernel 2: counting-sort top-1000 keys ----------------
__global__ __launch_bounds__(1024) void k_select(
    const uint64_t* __restrict__ keys,
    uint64_t* __restrict__ skeys, int* __restrict__ nvalid)
{
    __shared__ uint32_t hist[NB];
    __shared__ uint32_t base[NB];
    __shared__ uint32_t fill[NB];
    __shared__ uint64_t grouped[CAND_N];   // bin-grouped candidates (16 KiB)
    __shared__ uint64_t cand[CAND_N];      // rank-ordered keys (16 KiB)
    __shared__ int      s_misc[2];         // [0]=Bcut, [1]=target(V)

    int n = blockIdx.x, tid = threadIdx.x;

    if (tid < NB) { hist[tid] = 0; fill[tid] = 0; }
    for (int t = tid; t < CAND_N; t += 1024) cand[t] = ~0ull;
    __syncthreads();

    // pass 1: histogram valid keys
    #pragma unroll
    for (int it = 0; it < 9; ++it) {
        int t = tid + it * 1024;
        if (t < P_TOT) {
            uint64_t k = keys[(size_t)n * P_TOT + t];
            uint32_t dk = (uint32_t)(k >> 32);
            if (!(dk & 0x80000000u)) atomicAdd(&hist[(dk >> 17) - BINBASE], 1u);
        }
    }
    __syncthreads();

    // wave-0 prefix over 512 bins: per-bin exclusive base, total, cutoff bin
    if (tid < 64) {
        uint32_t c[8]; uint32_t s = 0;
        #pragma unroll
        for (int i = 0; i < 8; ++i) { c[i] = hist[tid * 8 + i]; s += c[i]; }
        uint32_t inc = s;
        #pragma unroll
        for (int o = 1; o < 64; o <<= 1) {
            uint32_t v = __shfl_up(inc, o);
            if (tid >= o) inc += v;
        }
        uint32_t excl = inc - s;
        uint32_t b = excl;
        #pragma unroll
        for (int i = 0; i < 8; ++i) { base[tid * 8 + i] = b; b += c[i]; }
        uint32_t total = __shfl(inc, 63);
        uint32_t target = total < (uint32_t)NMS_PRE ? total : (uint32_t)NMS_PRE;
        uint32_t cum = excl; int found = 0x7fffffff;
        #pragma unroll
        for (int i = 0; i < 8; ++i) {
            cum += c[i];
            if (found == 0x7fffffff && cum >= target && target > 0) found = tid * 8 + i;
        }
        #pragma unroll
        for (int o = 32; o > 0; o >>= 1) { int f = __shfl_xor(found, o); found = f < found ? f : found; }
        if (tid == 0) { s_misc[0] = (total > 0) ? found : -1; s_misc[1] = (int)target; }
    }
    __syncthreads();
    int Bcut = s_misc[0];

    // pass 2: scatter candidates (bins <= Bcut) into bin-grouped order (keys L2-warm)
    #pragma unroll
    for (int it = 0; it < 9; ++it) {
        int t = tid + it * 1024;
        if (t < P_TOT) {
            uint64_t k = keys[(size_t)n * P_TOT + t];
            uint32_t dk = (uint32_t)(k >> 32);
            if (!(dk & 0x80000000u)) {
                int bin = (int)((dk >> 17) - BINBASE);
                if (bin <= Bcut) {
                    uint32_t pos = base[bin] + atomicAdd(&fill[bin], 1u);
                    if (pos < CAND_N) grouped[pos] = k;
                }
            }
        }
    }
    __syncthreads();

    // exact rank within bin (keys unique -> total order identical to full sort)
    int ccnt = 0;
    if (Bcut >= 0) {
        uint32_t cc = base[Bcut] + hist[Bcut];
        ccnt = cc < (uint32_t)CAND_N ? (int)cc : CAND_N;
    }
    for (int s = tid; s < ccnt; s += 1024) {
        uint64_t k = grouped[s];
        uint32_t dk = (uint32_t)(k >> 32);
        int bin = (int)((dk >> 17) - BINBASE);
        uint32_t b0 = base[bin];
        uint32_t e0 = b0 + hist[bin]; if (e0 > (uint32_t)CAND_N) e0 = CAND_N;
        uint32_t r = b0;
        for (uint32_t t = b0; t < e0; ++t) r += (grouped[t] < k) ? 1u : 0u;
        if (r < (uint32_t)CAND_N) cand[r] = k;
    }
    __syncthreads();

    if (tid < NMS_PRE) skeys[n * NMS_PRE + tid] = cand[tid];
    if (tid == 0) nvalid[n] = s_misc[1];
}

// ---------------- Kernel 3: decode + gmax + greedy NMS + output ----------------
__global__ __launch_bounds__(256) void k_nms(
    const uint64_t* __restrict__ skeys, const int* __restrict__ nvalid,
    const float* __restrict__ reg0, const float* __restrict__ reg1, const float* __restrict__ reg2,
    float* __restrict__ out)
{
    __shared__ float4 s_obx[NMS_PRE];   // offset boxes  (16000 B)
    __shared__ float4 s_raw[NMS_PRE];   // raw boxes     (16000 B)
    __shared__ float2 s_sl[NMS_PRE];    // score,label   ( 8000 B)
    __shared__ float  s_oar[NMS_PRE];   // offset areas  ( 4000 B)
    __shared__ float  fsh[4];
    __shared__ int    kidx[MAXOUT];

    int n = blockIdx.x, tid = threadIdx.x;
    int lane = tid & 63, wv = tid >> 6;
    int V = nvalid[n];

    // decode 4 anchors per thread (t = tid + 256*it), exactly like reference
    float4 bx4[4]; float lab4[4];
    float m = 0.f;
    #pragma unroll
    for (int it = 0; it < 4; ++it) {
        int t = tid + it * 256;
        float4 bx = make_float4(0.f, 0.f, 0.f, 0.f);
        float scm = -1.0f, labf = 0.f;
        if (t < NMS_PRE) {
            uint64_t key = skeys[n * NMS_PRE + t];
            uint32_t dk = (uint32_t)(key >> 32);
            if (!(dk & 0x80000000u)) {
                uint32_t low = (uint32_t)key;
                int lab = (int)(low & 0xFFu);
                int p   = (int)(low >> 8);
                uint32_t ord = ~dk;
                scm = __uint_as_float(ord ^ 0x80000000u);   // valid => positive float

                const float* rg; int HW, q, W; float s;
                if (p < 6400)      { rg = reg0; HW = 6400; q = p;        W = 80; s = 8.f; }
                else if (p < 8000) { rg = reg1; HW = 1600; q = p - 6400; W = 40; s = 16.f; }
                else               { rg = reg2; HW = 400;  q = p - 8000; W = 20; s = 32.f; }

                float px = (float)(q % W) * s;   // exact
                float py = (float)(q / W) * s;   // exact
                const float* rb = rg + (size_t)n * 4 * HW + q;
                float dx = rb[0], dy = rb[HW], dw = rb[2 * HW], dh = rb[3 * HW];
                float cx = __fadd_rn(__fmul_rn(dx, s), px);
                float cy = __fadd_rn(__fmul_rn(dy, s), py);
                float hw = __fmul_rn(__fmul_rn(expf(dw), s), 0.5f);
                float hh = __fmul_rn(__fmul_rn(expf(dh), s), 0.5f);
                bx.x = __fsub_rn(cx, hw); bx.y = __fsub_rn(cy, hh);
                bx.z = __fadd_rn(cx, hw); bx.w = __fadd_rn(cy, hh);
                labf = (float)lab;
                m = fmaxf(m, fmaxf(fmaxf(fabsf(bx.x), fabsf(bx.y)), fmaxf(fabsf(bx.z), fabsf(bx.w))));
            }
            s_raw[t] = bx;
            s_sl[t]  = make_float2(scm, labf);
        }
        bx4[it] = bx; lab4[it] = labf;
    }

    // gmax = max|b| over the 1000 gathered boxes (4-wave reduce)
    #pragma unroll
    for (int o = 32; o > 0; o >>= 1) m = fmaxf(m, __shfl_xor(m, o));
    if (lane == 0) fsh[wv] = m;
    __syncthreads();
    float gmax = fmaxf(fmaxf(fsh[0], fsh[1]), fmaxf(fsh[2], fsh[3]));

    // stage offset boxes
    #pragma unroll
    for (int it = 0; it < 4; ++it) {
        int t = tid + it * 256;
        if (t < NMS_PRE) {
            float off = __fmul_rn(lab4[it], __fadd_rn(gmax, 1.0f)); // lab * (max|b| + 1)
            float x1 = __fadd_rn(bx4[it].x, off), y1 = __fadd_rn(bx4[it].y, off);
            float x2 = __fadd_rn(bx4[it].z, off), y2 = __fadd_rn(bx4[it].w, off);
            s_obx[t] = make_float4(x1, y1, x2, y2);
            s_oar[t] = __fmul_rn(__fsub_rn(x2, x1), __fsub_rn(y2, y1));
        }
    }
    __syncthreads();
    if (tid >= 64) return;      // wave 0 finishes alone

    // ---- greedy NMS: lanes = kept boxes; candidates serial with LDS-broadcast prefetch ----
    int count = 0;
    float k1x1 = 0.f, k1y1 = 0.f, k1x2 = 0.f, k1y2 = 0.f, k1a = 0.f;  // kept[lane]
    float k2x1 = 0.f, k2y1 = 0.f, k2x2 = 0.f, k2y2 = 0.f, k2a = 0.f;  // kept[lane+64]

    float4 nb = s_obx[0]; float na = s_oar[0];
    for (int i = 0; i < V && count < MAXOUT; ++i) {
        float4 cb = nb; float ca = na;
        int ip = (i + 1 < V) ? i + 1 : i;
        nb = s_obx[ip]; na = s_oar[ip];     // prefetch next candidate (indep of decision)

        bool sup = false;
        int c1 = count < 64 ? count : 64;
        if (lane < c1) {
            float ltx = fmaxf(k1x1, cb.x), lty = fmaxf(k1y1, cb.y);
            float rbx = fminf(k1x2, cb.z), rby = fminf(k1y2, cb.w);
            float w = fmaxf(__fsub_rn(rbx, ltx), 0.f);
            float h = fmaxf(__fsub_rn(rby, lty), 0.f);
            float inter = __fmul_rn(w, h);
            float denom = __fadd_rn(__fsub_rn(__fadd_rn(k1a, ca), inter), 1e-9f);
            sup = (inter / denom > NMS_THRF);
        }
        if (count > 64 && lane < count - 64) {
            float ltx = fmaxf(k2x1, cb.x), lty = fmaxf(k2y1, cb.y);
            float rbx = fminf(k2x2, cb.z), rby = fminf(k2y2, cb.w);
            float w = fmaxf(__fsub_rn(rbx, ltx), 0.f);
            float h = fmaxf(__fsub_rn(rby, lty), 0.f);
            float inter = __fmul_rn(w, h);
            float denom = __fadd_rn(__fsub_rn(__fadd_rn(k2a, ca), inter), 1e-9f);
            sup = sup || (inter / denom > NMS_THRF);
        }
        if (__ballot(sup) == 0ull) {
            if (lane == count)      { k1x1 = cb.x; k1y1 = cb.y; k1x2 = cb.z; k1y2 = cb.w; k1a = ca; }
            if (lane + 64 == count) { k2x1 = cb.x; k2y1 = cb.y; k2x2 = cb.z; k2y2 = cb.w; k2a = ca; }
            if (lane == 0) kidx[count] = i;
            ++count;
        }
    }

    float* ob = out;                          // [32*100*4]
    float* os = out + N_IMG * MAXOUT * 4;     // [32*100]
    float* ol = os + N_IMG * MAXOUT;          // [32*100] labels as float
    for (int mi = lane; mi < MAXOUT; mi += 64) {
        int o4 = (n * MAXOUT + mi) * 4;
        if (mi < count) {
            int i = kidx[mi];
            float4 b  = s_raw[i];
            float2 sl = s_sl[i];
            ob[o4 + 0] = b.x; ob[o4 + 1] = b.y; ob[o4 + 2] = b.z; ob[o4 + 3] = b.w;
            os[n * MAXOUT + mi] = sl.x;
            ol[n * MAXOUT + mi] = sl.y;
        } else {
            ob[o4 + 0] = 0.f; ob[o4 + 1] = 0.f; ob[o4 + 2] = 0.f; ob[o4 + 3] = 0.f;
            os[n * MAXOUT + mi] = 0.f;
            ol[n * MAXOUT + mi] = -1.f;
        }
    }
}

extern "C" void kernel_launch(void* const* d_in, const int* in_sizes, int n_in,
                              void* d_out, int out_size, void* d_ws, size_t ws_size,
                              hipStream_t stream)
{
    const float* cls0 = (const float*)d_in[0];
    const float* cls1 = (const float*)d_in[1];
    const float* cls2 = (const float*)d_in[2];
    const float* reg0 = (const float*)d_in[3];
    const float* reg1 = (const float*)d_in[4];
    const float* reg2 = (const float*)d_in[5];
    const float* obj0 = (const float*)d_in[6];
    const float* obj1 = (const float*)d_in[7];
    const float* obj2 = (const float*)d_in[8];

    uint64_t* keys  = (uint64_t*)d_ws;                              // 2.1 MB
    uint64_t* skeys = (uint64_t*)((char*)d_ws + (4u << 20));        // 256 KB
    int*     nvalid = (int*)((char*)d_ws + (4u << 20) + (512u << 10));
    float* out = (float*)d_out;

    k_score<<<(N_IMG * P_TOT) / 64, 256, 0, stream>>>(
        cls0, cls1, cls2, obj0, obj1, obj2, keys);
    k_select<<<N_IMG, 1024, 0, stream>>>(keys, skeys, nvalid);
    k_nms<<<N_IMG, 256, 0, stream>>>(skeys, nvalid, reg0, reg1, reg2, out);
}